// Round 6
// baseline (1181.000 us; speedup 1.0000x reference)
//
#include <hip/hip_runtime.h>
#include <hip/hip_bf16.h>

#define DEV __device__ __forceinline__

using bf16 = __hip_bfloat16;
typedef __attribute__((ext_vector_type(8))) short short8v;  // 8 bf16 = 4 VGPRs
typedef __attribute__((ext_vector_type(4))) float f32x4;

constexpr int Bq = 16, Tq = 1024, Eq = 1024, Gq = 4, Nq = 8, Dq = 128, Vq = 2048;
constexpr int M1 = Bq * Tq;        // 16384
constexpr int N1q = Gq * Nq * Dq;  // 4096
constexpr int K1 = Eq;             // 1024
constexpr int K2 = Nq * Dq;        // 1024
constexpr int N2 = Vq;             // 2048

DEV unsigned short bfu(float x) {
  union { bf16 h; unsigned short u; } cv;
  cv.h = __float2bfloat16(x);
  return cv.u;
}

DEV float rcp_(float x) { return __builtin_amdgcn_rcpf(x); }
DEV float sigm(float x) { return rcp_(1.0f + __expf(-x)); }
DEV float tanh_(float x) { return fmaf(2.0f, rcp_(1.0f + __expf(-2.0f * x)), -1.0f); }

// async global->LDS, 16B per lane; LDS dest is wave-uniform base + lane*16
#define GLD16(gp, lp)                                                       \
  __builtin_amdgcn_global_load_lds(                                        \
      (const __attribute__((address_space(1))) void*)(gp),                 \
      (__attribute__((address_space(3))) void*)(lp), 16, 0, 0)

// ---------------------------------------------------------------------------
// Prep kernels: casts + transpose-cast
// ---------------------------------------------------------------------------
__global__ __launch_bounds__(256) void cast_f32_bf16(const float* __restrict__ s,
                                                     bf16* __restrict__ d, int n4) {
  const int i = blockIdx.x * 256 + threadIdx.x;
  if (i >= n4) return;
  const float4 v = ((const float4*)s)[i];
  ushort4 u;
  u.x = bfu(v.x); u.y = bfu(v.y); u.z = bfu(v.z); u.w = bfu(v.w);
  ((ushort4*)d)[i] = u;
}

// s: [SK][SN] f32 row-major  ->  d: [SN][SK] bf16 row-major
__global__ __launch_bounds__(256) void transpose_cast(const float* __restrict__ s,
                                                      bf16* __restrict__ d,
                                                      int SK, int SN) {
  __shared__ float t[32][33];
  const int n0 = blockIdx.x * 32, k0 = blockIdx.y * 32;
  const int tx = threadIdx.x & 31, ty = threadIdx.x >> 5;  // ty: 0..7
#pragma unroll
  for (int i = 0; i < 32; i += 8)
    t[ty + i][tx] = s[(size_t)(k0 + ty + i) * SN + n0 + tx];
  __syncthreads();
#pragma unroll
  for (int i = 0; i < 32; i += 8)
    d[(size_t)(n0 + ty + i) * SK + k0 + tx] = __float2bfloat16(t[tx][ty + i]);
}

// ---------------------------------------------------------------------------
// bf16 MFMA GEMM, m97 structure: C[M,N] = A[M,K] @ Bt[N,K]^T
// MODE 0: f32 out + bias.  MODE 2: bf16 out scattered to Wx_rec[b,n,t,d,g].
// ---------------------------------------------------------------------------
template <int MODE>
__global__ __launch_bounds__(256) void gemm_bt(const bf16* __restrict__ A,
                                               const bf16* __restrict__ Bt,
                                               void* __restrict__ Cout,
                                               const float* __restrict__ bp,
                                               int K, int N) {
  __shared__ bf16 As[128 * 32];
  __shared__ bf16 Bs[128 * 32];
  const int m0 = blockIdx.y * 128, n0 = blockIdx.x * 128;
  const int tid = threadIdx.x;
  const int lane = tid & 63, w = tid >> 6;
  const int wm = w >> 1, wn = w & 1;

  const int srow = lane >> 2, scol = (lane & 3) * 8;
  const int ca = w * 2;
  const bf16* Ag0 = A + (size_t)(m0 + ca * 16 + srow) * K + scol;
  const bf16* Ag1 = Ag0 + (size_t)16 * K;
  const bf16* Bg0 = Bt + (size_t)(n0 + ca * 16 + srow) * K + scol;
  const bf16* Bg1 = Bg0 + (size_t)16 * K;
  bf16* Al0 = As + ca * 512;
  bf16* Al1 = Al0 + 512;
  bf16* Bl0 = Bs + ca * 512;
  bf16* Bl1 = Bl0 + 512;

  f32x4 acc[4][4] = {};

  const int rr = lane & 15;
  const int kb = (lane >> 4) * 8;

  for (int k0 = 0; k0 < K; k0 += 32) {
    GLD16(Ag0 + k0, Al0);
    GLD16(Ag1 + k0, Al1);
    GLD16(Bg0 + k0, Bl0);
    GLD16(Bg1 + k0, Bl1);
    __syncthreads();
    short8v af[4], bfr[4];
#pragma unroll
    for (int i = 0; i < 4; ++i) {
      af[i]  = *(const short8v*)&As[(wm * 64 + i * 16 + rr) * 32 + kb];
      bfr[i] = *(const short8v*)&Bs[(wn * 64 + i * 16 + rr) * 32 + kb];
    }
#pragma unroll
    for (int i = 0; i < 4; ++i)
#pragma unroll
      for (int j = 0; j < 4; ++j)
        acc[i][j] = __builtin_amdgcn_mfma_f32_16x16x32_bf16(af[i], bfr[j], acc[i][j], 0, 0, 0);
    __syncthreads();
  }

  const int crow = (lane >> 4) * 4, ccol = lane & 15;
  if constexpr (MODE == 2) {
    // scatter: row=(b,t), col=(g,n,d) -> Wx_rec[((b*8+n)*1024+t)*512 + d*4 + g]
    bf16* C = (bf16*)Cout;
#pragma unroll
    for (int i = 0; i < 4; ++i)
#pragma unroll
      for (int j = 0; j < 4; ++j) {
        const int col = n0 + wn * 64 + j * 16 + ccol;
        const int g = col >> 10, nn = (col >> 7) & 7, dd = col & 127;
#pragma unroll
        for (int jj = 0; jj < 4; ++jj) {
          const int row = m0 + wm * 64 + i * 16 + crow + jj;
          const int b = row >> 10, t = row & 1023;
          C[(((size_t)(b * 8 + nn) * 1024 + t) << 9) + dd * 4 + g] =
              __float2bfloat16(acc[i][j][jj]);
        }
      }
  } else {
    float* C = (float*)Cout;
    float bv[4];
#pragma unroll
    for (int j = 0; j < 4; ++j) bv[j] = bp[n0 + wn * 64 + j * 16 + ccol];
#pragma unroll
    for (int i = 0; i < 4; ++i)
#pragma unroll
      for (int j = 0; j < 4; ++j) {
        const size_t base =
            (size_t)(m0 + wm * 64 + i * 16 + crow) * N + (n0 + wn * 64 + j * 16 + ccol);
#pragma unroll
        for (int jj = 0; jj < 4; ++jj)
          C[base + (size_t)jj * N] = acc[i][j][jj] + bv[j];
      }
  }
}

// ---------------------------------------------------------------------------
// LSTM recurrence via MFMA broadcast. v6: TWO chains per WG sharing R.
// WG (wg<64): head n = wg&7, chains (bb, n) and (bb+8, n) where bb = wg>>3.
// The per-step serial latency (ds_write -> barrier -> ds_read -> MFMA -> act)
// is amortized over 2 independent chains whose work interleaves.
// ---------------------------------------------------------------------------
__global__ __launch_bounds__(512) void lstm_mfma(const bf16* __restrict__ Wx,
                                                 const float* __restrict__ R,
                                                 const float* __restrict__ bias,
                                                 bf16* __restrict__ h_all) {
  const int wg = blockIdx.x;
  const int bb = wg >> 3;   // batch base (0..7): chains bb and bb+8
  const int n = wg & 7;     // head
  const int tid = threadIdx.x;
  const int w = tid >> 6, lane = tid & 63;
  const int lg = lane >> 4;        // k-slice group 0..3
  const int lc = lane & 15;        // col within fragment
  const int d = w * 16 + lc;       // this lane's d

  // B fragments (SHARED by both chains): R[g, n, d, 32*kf + 8*lg + j]
  short8v Bf[4][4];
#pragma unroll
  for (int g = 0; g < 4; ++g)
#pragma unroll
    for (int kf = 0; kf < 4; ++kf) {
      const float* rp = R + (size_t)((g * Nq + n) * Dq + d) * Dq + 32 * kf + 8 * lg;
      const float4 r0 = *(const float4*)rp;
      const float4 r1 = *(const float4*)(rp + 4);
      short8v bv;
      bv[0] = (short)bfu(r0.x); bv[1] = (short)bfu(r0.y);
      bv[2] = (short)bfu(r0.z); bv[3] = (short)bfu(r0.w);
      bv[4] = (short)bfu(r1.x); bv[5] = (short)bfu(r1.y);
      bv[6] = (short)bfu(r1.z); bv[7] = (short)bfu(r1.w);
      Bf[g][kf] = bv;
    }

  float bvf[4];
#pragma unroll
  for (int g = 0; g < 4; ++g) bvf[g] = bias[(g * Nq + n) * Dq + d];

  __shared__ __align__(16) bf16 hbuf[2][2][128];  // [chain][dbuf][d]
  if (tid < 128) {
    hbuf[0][0][tid] = __float2bfloat16(0.f);
    hbuf[1][0][tid] = __float2bfloat16(0.f);
  }
  __syncthreads();

  // Wx_rec layout: [(b*8+n)*1024 + t][d*4 + g], row = 512 bf16
  const bf16* wxA = Wx + ((size_t)(bb * 8 + n) << 19) + d * 4;
  const bf16* wxB = Wx + ((size_t)((bb + 8) * 8 + n) << 19) + d * 4;
  bf16* hpA = h_all + ((size_t)(bb * Tq) * Nq + n) * Dq + d;
  bf16* hpB = h_all + ((size_t)((bb + 8) * Tq) * Nq + n) * Dq + d;

  // 4-deep static prefetch pipeline: one 8B load per step per chain
  ushort4 wxrA[4], wxrB[4];
#pragma unroll
  for (int u = 0; u < 4; ++u) {
    wxrA[u] = *(const ushort4*)(wxA + ((size_t)u << 9));
    wxrB[u] = *(const ushort4*)(wxB + ((size_t)u << 9));
  }

  float cA = 0.f, cB = 0.f;

  for (int t0 = 0; t0 < Tq; t0 += 4) {
#pragma unroll
    for (int u = 0; u < 4; ++u) {
      const int t = t0 + u;
      const bf16* hA = hbuf[0][t & 1];
      const bf16* hB = hbuf[1][t & 1];
      short8v AfA[4], AfB[4];
#pragma unroll
      for (int kf = 0; kf < 4; ++kf) {
        AfA[kf] = *(const short8v*)(hA + 32 * kf + 8 * lg);
        AfB[kf] = *(const short8v*)(hB + 32 * kf + 8 * lg);
      }

      // decode wx (4 gates each, bf16 bits -> f32)
      float wxfA[4], wxfB[4];
      wxfA[0] = __uint_as_float((unsigned)wxrA[u].x << 16);
      wxfA[1] = __uint_as_float((unsigned)wxrA[u].y << 16);
      wxfA[2] = __uint_as_float((unsigned)wxrA[u].z << 16);
      wxfA[3] = __uint_as_float((unsigned)wxrA[u].w << 16);
      wxfB[0] = __uint_as_float((unsigned)wxrB[u].x << 16);
      wxfB[1] = __uint_as_float((unsigned)wxrB[u].y << 16);
      wxfB[2] = __uint_as_float((unsigned)wxrB[u].z << 16);
      wxfB[3] = __uint_as_float((unsigned)wxrB[u].w << 16);

      // single depth-4 accumulator chain per gate per chain
      // (8 independent MFMA chains interleave -> latency hidden)
      f32x4 aA[4], aB[4];
#pragma unroll
      for (int g = 0; g < 4; ++g) {
        const float pA = wxfA[g] + bvf[g];
        const float pB = wxfB[g] + bvf[g];
        aA[g][0] = pA; aA[g][1] = pA; aA[g][2] = pA; aA[g][3] = pA;
        aB[g][0] = pB; aB[g][1] = pB; aB[g][2] = pB; aB[g][3] = pB;
      }
#pragma unroll
      for (int kf = 0; kf < 4; ++kf)
#pragma unroll
        for (int g = 0; g < 4; ++g) {
          aA[g] = __builtin_amdgcn_mfma_f32_16x16x32_bf16(AfA[kf], Bf[g][kf], aA[g], 0, 0, 0);
          aB[g] = __builtin_amdgcn_mfma_f32_16x16x32_bf16(AfB[kf], Bf[g][kf], aB[g], 0, 0, 0);
        }

      // prefetch wx for step t+4 into the SAME static slot
      {
        const int tp = (t + 4 < Tq) ? (t + 4) : (Tq - 1);
        wxrA[u] = *(const ushort4*)(wxA + ((size_t)tp << 9));
        wxrB[u] = *(const ushort4*)(wxB + ((size_t)tp << 9));
      }

      const float iA = sigm(aA[0][0]);
      const float fA = sigm(aA[1][0]);
      const float zA = tanh_(aA[2][0]);
      const float oA = sigm(aA[3][0]);
      cA = fA * cA + iA * zA;
      const float hAv = oA * tanh_(cA);
      const bf16 hA16 = __float2bfloat16(hAv);

      const float iB = sigm(aB[0][0]);
      const float fB = sigm(aB[1][0]);
      const float zB = tanh_(aB[2][0]);
      const float oB = sigm(aB[3][0]);
      cB = fB * cB + iB * zB;
      const float hBv = oB * tanh_(cB);
      const bf16 hB16 = __float2bfloat16(hBv);

      if (lg == 0) {
        hbuf[0][(t + 1) & 1][d] = hA16;
        hbuf[1][(t + 1) & 1][d] = hB16;
        hpA[(size_t)t * (Nq * Dq)] = hA16;
        hpB[(size_t)t * (Nq * Dq)] = hB16;
      }
      // barrier WITHOUT vmcnt drain: only LDS visibility needed.
      __builtin_amdgcn_sched_barrier(0);
      asm volatile("s_waitcnt lgkmcnt(0)" ::: "memory");
      __builtin_amdgcn_sched_barrier(0);
      __builtin_amdgcn_s_barrier();
      __builtin_amdgcn_sched_barrier(0);
    }
  }
}

// ---------------------------------------------------------------------------
extern "C" void kernel_launch(void* const* d_in, const int* in_sizes, int n_in,
                              void* d_out, int out_size, void* d_ws, size_t ws_size,
                              hipStream_t stream) {
  const float* x_emb = (const float*)d_in[0];  // [16,1024,1024]
  const float* W_in  = (const float*)d_in[1];  // [1024,4096]
  const float* R     = (const float*)d_in[2];  // [4,8,128,128]
  const float* bias  = (const float*)d_in[3];  // [4,8,128]
  const float* W_prj = (const float*)d_in[4];  // [2048,1024]
  const float* b_prj = (const float*)d_in[5];  // [2048]

  char* ws = (char*)d_ws;
  bf16* xb  = (bf16*)ws;                               // 32 MB
  bf16* WiT = (bf16*)(ws + (size_t)M1 * K1 * 2);       //  8 MB
  bf16* Wpb = WiT + (size_t)N1q * K1;                  //  4 MB
  bf16* H   = Wpb + (size_t)N2 * K2;                   // 32 MB
  bf16* Wx = (bf16*)d_out;                             // 134 MB, dead before gemm_out

  cast_f32_bf16<<<(M1 * K1 / 4 + 255) / 256, 256, 0, stream>>>(x_emb, xb, M1 * K1 / 4);
  transpose_cast<<<dim3(N1q / 32, K1 / 32), 256, 0, stream>>>(W_in, WiT, K1, N1q);
  cast_f32_bf16<<<(N2 * K2 / 4 + 255) / 256, 256, 0, stream>>>(W_prj, Wpb, N2 * K2 / 4);

  gemm_bt<2><<<dim3(N1q / 128, M1 / 128), 256, 0, stream>>>(
      xb, WiT, (void*)Wx, nullptr, K1, N1q);

  lstm_mfma<<<dim3(64), 512, 0, stream>>>(Wx, R, bias, H);

  gemm_bt<0><<<dim3(N2 / 128, M1 / 128), 256, 0, stream>>>(
      H, Wpb, d_out, b_prj, K2, N2);
}

// Round 7
// 798.275 us; speedup vs baseline: 1.4794x; 1.4794x over previous
//
#include <hip/hip_runtime.h>
#include <hip/hip_bf16.h>

#define DEV __device__ __forceinline__

using bf16 = __hip_bfloat16;
typedef __attribute__((ext_vector_type(8))) short short8v;  // 8 bf16 = 4 VGPRs
typedef __attribute__((ext_vector_type(4))) float f32x4;

constexpr int Bq = 16, Tq = 1024, Eq = 1024, Gq = 4, Nq = 8, Dq = 128, Vq = 2048;
constexpr int M1 = Bq * Tq;        // 16384
constexpr int N1q = Gq * Nq * Dq;  // 4096
constexpr int K1 = Eq;             // 1024
constexpr int K2 = Nq * Dq;        // 1024
constexpr int N2 = Vq;             // 2048

DEV unsigned short bfu(float x) {
  union { bf16 h; unsigned short u; } cv;
  cv.h = __float2bfloat16(x);
  return cv.u;
}

DEV float rcp_(float x) { return __builtin_amdgcn_rcpf(x); }
DEV float sigm(float x) { return rcp_(1.0f + __expf(-x)); }
DEV float tanh_(float x) { return fmaf(2.0f, rcp_(1.0f + __expf(-2.0f * x)), -1.0f); }

// async global->LDS, 16B per lane; LDS dest is wave-uniform base + lane*16
#define GLD16(gp, lp)                                                       \
  __builtin_amdgcn_global_load_lds(                                        \
      (const __attribute__((address_space(1))) void*)(gp),                 \
      (__attribute__((address_space(3))) void*)(lp), 16, 0, 0)

// ---------------------------------------------------------------------------
// Prep kernels: casts + transpose-cast
// ---------------------------------------------------------------------------
__global__ __launch_bounds__(256) void cast_f32_bf16(const float* __restrict__ s,
                                                     bf16* __restrict__ d, int n4) {
  const int i = blockIdx.x * 256 + threadIdx.x;
  if (i >= n4) return;
  const float4 v = ((const float4*)s)[i];
  ushort4 u;
  u.x = bfu(v.x); u.y = bfu(v.y); u.z = bfu(v.z); u.w = bfu(v.w);
  ((ushort4*)d)[i] = u;
}

// s: [SK][SN] f32 row-major  ->  d: [SN][SK] bf16 row-major
__global__ __launch_bounds__(256) void transpose_cast(const float* __restrict__ s,
                                                      bf16* __restrict__ d,
                                                      int SK, int SN) {
  __shared__ float t[32][33];
  const int n0 = blockIdx.x * 32, k0 = blockIdx.y * 32;
  const int tx = threadIdx.x & 31, ty = threadIdx.x >> 5;  // ty: 0..7
#pragma unroll
  for (int i = 0; i < 32; i += 8)
    t[ty + i][tx] = s[(size_t)(k0 + ty + i) * SN + n0 + tx];
  __syncthreads();
#pragma unroll
  for (int i = 0; i < 32; i += 8)
    d[(size_t)(n0 + ty + i) * SK + k0 + tx] = __float2bfloat16(t[tx][ty + i]);
}

// ---------------------------------------------------------------------------
// bf16 MFMA GEMM, m97 structure: C[M,N] = A[M,K] @ Bt[N,K]^T
// MODE 0: f32 out + bias.  MODE 2: bf16 out scattered to Wx_rec[b,n,t,d,g].
// ---------------------------------------------------------------------------
template <int MODE>
__global__ __launch_bounds__(256) void gemm_bt(const bf16* __restrict__ A,
                                               const bf16* __restrict__ Bt,
                                               void* __restrict__ Cout,
                                               const float* __restrict__ bp,
                                               int K, int N) {
  __shared__ bf16 As[128 * 32];
  __shared__ bf16 Bs[128 * 32];
  const int m0 = blockIdx.y * 128, n0 = blockIdx.x * 128;
  const int tid = threadIdx.x;
  const int lane = tid & 63, w = tid >> 6;
  const int wm = w >> 1, wn = w & 1;

  const int srow = lane >> 2, scol = (lane & 3) * 8;
  const int ca = w * 2;
  const bf16* Ag0 = A + (size_t)(m0 + ca * 16 + srow) * K + scol;
  const bf16* Ag1 = Ag0 + (size_t)16 * K;
  const bf16* Bg0 = Bt + (size_t)(n0 + ca * 16 + srow) * K + scol;
  const bf16* Bg1 = Bg0 + (size_t)16 * K;
  bf16* Al0 = As + ca * 512;
  bf16* Al1 = Al0 + 512;
  bf16* Bl0 = Bs + ca * 512;
  bf16* Bl1 = Bl0 + 512;

  f32x4 acc[4][4] = {};

  const int rr = lane & 15;
  const int kb = (lane >> 4) * 8;

  for (int k0 = 0; k0 < K; k0 += 32) {
    GLD16(Ag0 + k0, Al0);
    GLD16(Ag1 + k0, Al1);
    GLD16(Bg0 + k0, Bl0);
    GLD16(Bg1 + k0, Bl1);
    __syncthreads();
    short8v af[4], bfr[4];
#pragma unroll
    for (int i = 0; i < 4; ++i) {
      af[i]  = *(const short8v*)&As[(wm * 64 + i * 16 + rr) * 32 + kb];
      bfr[i] = *(const short8v*)&Bs[(wn * 64 + i * 16 + rr) * 32 + kb];
    }
#pragma unroll
    for (int i = 0; i < 4; ++i)
#pragma unroll
      for (int j = 0; j < 4; ++j)
        acc[i][j] = __builtin_amdgcn_mfma_f32_16x16x32_bf16(af[i], bfr[j], acc[i][j], 0, 0, 0);
    __syncthreads();
  }

  const int crow = (lane >> 4) * 4, ccol = lane & 15;
  if constexpr (MODE == 2) {
    // scatter: row=(b,t), col=(g,n,d) -> Wx_rec[((b*8+n)*1024+t)*512 + d*4 + g]
    bf16* C = (bf16*)Cout;
#pragma unroll
    for (int i = 0; i < 4; ++i)
#pragma unroll
      for (int j = 0; j < 4; ++j) {
        const int col = n0 + wn * 64 + j * 16 + ccol;
        const int g = col >> 10, nn = (col >> 7) & 7, dd = col & 127;
#pragma unroll
        for (int jj = 0; jj < 4; ++jj) {
          const int row = m0 + wm * 64 + i * 16 + crow + jj;
          const int b = row >> 10, t = row & 1023;
          C[(((size_t)(b * 8 + nn) * 1024 + t) << 9) + dd * 4 + g] =
              __float2bfloat16(acc[i][j][jj]);
        }
      }
  } else {
    float* C = (float*)Cout;
    float bv[4];
#pragma unroll
    for (int j = 0; j < 4; ++j) bv[j] = bp[n0 + wn * 64 + j * 16 + ccol];
#pragma unroll
    for (int i = 0; i < 4; ++i)
#pragma unroll
      for (int j = 0; j < 4; ++j) {
        const size_t base =
            (size_t)(m0 + wm * 64 + i * 16 + crow) * N + (n0 + wn * 64 + j * 16 + ccol);
#pragma unroll
        for (int jj = 0; jj < 4; ++jj)
          C[base + (size_t)jj * N] = acc[i][j][jj] + bv[j];
      }
  }
}

// ---------------------------------------------------------------------------
// LSTM recurrence via MFMA broadcast. One WG per (b,n) chain, 8 waves.
// v7 (lean-issue) vs r5:
//  - persistent accumulators: only element 0 written per step (8 v_mov vs 64;
//    elements 1-3 carry stale values that never touch element 0).
//  - depth-2 MFMA chains (2 chains of 2 per gate), one final add per gate.
//  - step is per-SIMD issue-bound (r6 evidence), so every saved op counts.
// ---------------------------------------------------------------------------
__global__ __launch_bounds__(512) void lstm_mfma(const bf16* __restrict__ Wx,
                                                 const float* __restrict__ R,
                                                 const float* __restrict__ bias,
                                                 bf16* __restrict__ h_all) {
  const int wg = blockIdx.x;
  const int bb = wg >> 3;   // batch
  const int n = wg & 7;     // head
  const int tid = threadIdx.x;
  const int w = tid >> 6, lane = tid & 63;
  const int lg = lane >> 4;        // k-slice group 0..3
  const int lc = lane & 15;        // col within fragment
  const int d = w * 16 + lc;       // this lane's d

  // B fragments: lane holds R[g, n, d, 32*kf + 8*lg + j], j=0..7 (bf16)
  short8v Bf[4][4];
#pragma unroll
  for (int g = 0; g < 4; ++g)
#pragma unroll
    for (int kf = 0; kf < 4; ++kf) {
      const float* rp = R + (size_t)((g * Nq + n) * Dq + d) * Dq + 32 * kf + 8 * lg;
      const float4 r0 = *(const float4*)rp;
      const float4 r1 = *(const float4*)(rp + 4);
      short8v bv;
      bv[0] = (short)bfu(r0.x); bv[1] = (short)bfu(r0.y);
      bv[2] = (short)bfu(r0.z); bv[3] = (short)bfu(r0.w);
      bv[4] = (short)bfu(r1.x); bv[5] = (short)bfu(r1.y);
      bv[6] = (short)bfu(r1.z); bv[7] = (short)bfu(r1.w);
      Bf[g][kf] = bv;
    }

  float bvf[4];
#pragma unroll
  for (int g = 0; g < 4; ++g) bvf[g] = bias[(g * Nq + n) * Dq + d];

  __shared__ __align__(16) bf16 hbuf[2][128];
  if (tid < 128) hbuf[0][tid] = __float2bfloat16(0.f);
  __syncthreads();

  // Wx_rec layout: [(b*8+n)*1024 + t][d*4 + g], row size 512 bf16
  const bf16* wx0 = Wx + ((size_t)(bb * 8 + n) << 19) + d * 4;
  bf16* hallp = h_all + ((size_t)(bb * Tq) * Nq + n) * Dq + d;

  // 4-deep static prefetch pipeline: one 8B load per step
  ushort4 wxr[4];
#pragma unroll
  for (int u = 0; u < 4; ++u)
    wxr[u] = *(const ushort4*)(wx0 + ((size_t)u << 9));

  float c = 0.f;
  // persistent accumulators: elements 1-3 are don't-care (never read);
  // init once so all lanes hold defined values.
  f32x4 accA[4] = {}, accB[4] = {};

  for (int t0 = 0; t0 < Tq; t0 += 4) {
#pragma unroll
    for (int u = 0; u < 4; ++u) {
      const int t = t0 + u;
      // A fragments: every lane reads h[32*kf + 8*lg .. +8] (broadcast groups)
      const bf16* hb = hbuf[t & 1];
      short8v Af0 = *(const short8v*)(hb + 8 * lg);
      short8v Af1 = *(const short8v*)(hb + 32 + 8 * lg);
      short8v Af2 = *(const short8v*)(hb + 64 + 8 * lg);
      short8v Af3 = *(const short8v*)(hb + 96 + 8 * lg);

      // decode this step's wx (4 gates) and set ONLY element 0 of the accs
#pragma unroll
      for (int g = 0; g < 4; ++g) {
        const unsigned ub = (g == 0) ? wxr[u].x : (g == 1) ? wxr[u].y
                          : (g == 2) ? wxr[u].z : wxr[u].w;
        accA[g][0] = __uint_as_float(ub << 16) + bvf[g];
        accB[g][0] = 0.f;
      }

      // depth-2 MFMA chains: accA gets kf 0,1; accB gets kf 2,3
#pragma unroll
      for (int g = 0; g < 4; ++g) {
        accA[g] = __builtin_amdgcn_mfma_f32_16x16x32_bf16(Af0, Bf[g][0], accA[g], 0, 0, 0);
        accB[g] = __builtin_amdgcn_mfma_f32_16x16x32_bf16(Af2, Bf[g][2], accB[g], 0, 0, 0);
      }
#pragma unroll
      for (int g = 0; g < 4; ++g) {
        accA[g] = __builtin_amdgcn_mfma_f32_16x16x32_bf16(Af1, Bf[g][1], accA[g], 0, 0, 0);
        accB[g] = __builtin_amdgcn_mfma_f32_16x16x32_bf16(Af3, Bf[g][3], accB[g], 0, 0, 0);
      }

      // prefetch wx for step t+4 into the SAME static slot
      {
        const int tp = (t + 4 < Tq) ? (t + 4) : (Tq - 1);
        wxr[u] = *(const ushort4*)(wx0 + ((size_t)tp << 9));
      }

      const float i_ = sigm(accA[0][0] + accB[0][0]);
      const float f_ = sigm(accA[1][0] + accB[1][0]);
      const float z_ = tanh_(accA[2][0] + accB[2][0]);
      const float o_ = sigm(accA[3][0] + accB[3][0]);
      c = f_ * c + i_ * z_;
      const float h = o_ * tanh_(c);
      const bf16 h16 = __float2bfloat16(h);

      if (lg == 0) {
        hbuf[(t + 1) & 1][d] = h16;
        hallp[(size_t)t * (Nq * Dq)] = h16;
      }
      // barrier WITHOUT vmcnt drain: only LDS visibility needed.
      __builtin_amdgcn_sched_barrier(0);
      asm volatile("s_waitcnt lgkmcnt(0)" ::: "memory");
      __builtin_amdgcn_sched_barrier(0);
      __builtin_amdgcn_s_barrier();
      __builtin_amdgcn_sched_barrier(0);
    }
  }
}

// ---------------------------------------------------------------------------
extern "C" void kernel_launch(void* const* d_in, const int* in_sizes, int n_in,
                              void* d_out, int out_size, void* d_ws, size_t ws_size,
                              hipStream_t stream) {
  const float* x_emb = (const float*)d_in[0];  // [16,1024,1024]
  const float* W_in  = (const float*)d_in[1];  // [1024,4096]
  const float* R     = (const float*)d_in[2];  // [4,8,128,128]
  const float* bias  = (const float*)d_in[3];  // [4,8,128]
  const float* W_prj = (const float*)d_in[4];  // [2048,1024]
  const float* b_prj = (const float*)d_in[5];  // [2048]

  char* ws = (char*)d_ws;
  bf16* xb  = (bf16*)ws;                               // 32 MB
  bf16* WiT = (bf16*)(ws + (size_t)M1 * K1 * 2);       //  8 MB
  bf16* Wpb = WiT + (size_t)N1q * K1;                  //  4 MB
  bf16* H   = Wpb + (size_t)N2 * K2;                   // 32 MB
  bf16* Wx = (bf16*)d_out;                             // 134 MB, dead before gemm_out

  cast_f32_bf16<<<(M1 * K1 / 4 + 255) / 256, 256, 0, stream>>>(x_emb, xb, M1 * K1 / 4);
  transpose_cast<<<dim3(N1q / 32, K1 / 32), 256, 0, stream>>>(W_in, WiT, K1, N1q);
  cast_f32_bf16<<<(N2 * K2 / 4 + 255) / 256, 256, 0, stream>>>(W_prj, Wpb, N2 * K2 / 4);

  gemm_bt<2><<<dim3(N1q / 128, M1 / 128), 256, 0, stream>>>(
      xb, WiT, (void*)Wx, nullptr, K1, N1q);

  lstm_mfma<<<dim3(Bq * Nq), 512, 0, stream>>>(Wx, R, bias, H);

  gemm_bt<0><<<dim3(N2 / 128, M1 / 128), 256, 0, stream>>>(
      H, Wpb, d_out, b_prj, K2, N2);
}